// Round 6
// baseline (543.329 us; speedup 1.0000x reference)
//
#include <hip/hip_runtime.h>

#define NN 100000
#define D 64
#define BN_EPS 1e-5f

// ---------------- degree ----------------
__global__ void k_deg_init(float* deg, int n) {
    int i = blockIdx.x * blockDim.x + threadIdx.x;
    if (i < n) deg[i] = 1.0f;  // self-loop weight
}

__global__ void k_deg_edges(const int* __restrict__ src, const int* __restrict__ dst,
                            float* deg, int E) {
    int t = blockIdx.x * blockDim.x + threadIdx.x;
    int e0 = t * 8;
#pragma unroll
    for (int j = 0; j < 8; ++j) {
        int e = e0 + j;
        if (e < E) {
            int s = src[e], d = dst[e];
            if (s != d) atomicAdd(&deg[d], 1.0f);
        }
    }
}

__global__ void k_dinv_f(float* deg, int n) {
    int i = blockIdx.x * blockDim.x + threadIdx.x;
    if (i < n) deg[i] = rsqrtf(deg[i]);  // deg >= 1 always
}

// ---------------- out init: self-loop term (float4) ----------------
__global__ void k_agg_init(const float* __restrict__ x, const float* __restrict__ dinv,
                           float* __restrict__ out, int n) {
    int i = blockIdx.x * blockDim.x + threadIdx.x;  // one float4 per thread
    int total = n * (D / 4);
    if (i >= total) return;
    int row = i >> 4;  // 16 float4 per row
    float di = dinv[row];
    float s = di * di;
    float4 v = ((const float4*)x)[i];
    v.x *= s; v.y *= s; v.z *= s; v.w *= s;
    ((float4*)out)[i] = v;
}

// ---------------- edge scatter: 8 edges per wave, lane = channel ----------------
__global__ __launch_bounds__(256) void k_scatter8(const int* __restrict__ src,
                                                  const int* __restrict__ dst,
                                                  const float* __restrict__ x,
                                                  const float* __restrict__ dinv,
                                                  float* out, int E) {
    int gw = blockIdx.x * 4 + (threadIdx.x >> 6);
    int lane = threadIdx.x & 63;
    int e0 = gw * 8;
    if (e0 >= E) return;

    int s[8], d[8];
    float w[8];
#pragma unroll
    for (int j = 0; j < 8; ++j) {
        int e = e0 + j;
        int ec = e < E ? e : E - 1;
        s[j] = src[ec];
        d[j] = dst[ec];
    }
#pragma unroll
    for (int j = 0; j < 8; ++j) {
        int e = e0 + j;
        w[j] = (e < E && s[j] != d[j]) ? dinv[s[j]] * dinv[d[j]] : 0.0f;
    }
    float v[8];
#pragma unroll
    for (int j = 0; j < 8; ++j) {
        v[j] = x[(size_t)s[j] * D + lane];  // all 8 row-loads in flight
    }
#pragma unroll
    for (int j = 0; j < 8; ++j) {
        if (w[j] != 0.0f)
            atomicAdd(&out[(size_t)d[j] * D + lane], v[j] * w[j]);  // fire-and-forget
    }
}

// ---------------- GEMM (in place) fused with BN stats ----------------
__global__ void k_zero_stats(float* sums) {
    int i = threadIdx.x;
    if (i < 128) sums[i] = 0.0f;
}

// grid-stride at 1024 blocks: partial sums in registers, one 128-atomic
// flush per block (proven in R4->R5: no same-line atomic pileup).
__global__ __launch_bounds__(256) void k_gemm_stats(float* __restrict__ out,
                                                    const float* __restrict__ W,
                                                    float* sums, int n) {
    __shared__ float Ws[64 * 64];
    int tid = threadIdx.x;
    for (int i = tid; i < 64 * 64; i += 256) Ws[i] = W[i];
    __syncthreads();
    int wave = tid >> 6, lane = tid & 63;
    float s = 0.0f, sq = 0.0f;
    for (int row = blockIdx.x * 4 + wave; row < n; row += gridDim.x * 4) {
        float xv = out[(size_t)row * D + lane];
        float acc = 0.0f;
#pragma unroll
        for (int k = 0; k < 64; ++k) {
            acc += __shfl(xv, k) * Ws[k * 64 + lane];
        }
        out[(size_t)row * D + lane] = acc;
        s += acc;
        sq += acc * acc;
    }
    __shared__ float ls[4][64], lq[4][64];
    ls[wave][lane] = s;
    lq[wave][lane] = sq;
    __syncthreads();
    if (wave == 0) {
        float ts = ls[0][lane] + ls[1][lane] + ls[2][lane] + ls[3][lane];
        float tq = lq[0][lane] + lq[1][lane] + lq[2][lane] + lq[3][lane];
        atomicAdd(&sums[lane], ts);
        atomicAdd(&sums[64 + lane], tq);
    }
}

// ---------------- BN apply + ReLU (float4, in place) ----------------
// GCN bias b cancels exactly in BatchNorm: omitted.
__global__ void k_bn_apply(float* out, const float* __restrict__ sums,
                           const float* __restrict__ bnw, const float* __restrict__ bnb,
                           int n) {
    int i = blockIdx.x * blockDim.x + threadIdx.x;  // one float4 per thread
    int total = n * (D / 4);
    if (i >= total) return;
    int c0 = (i * 4) & 63;
    const float invn = 1.0f / (float)NN;
    float4 v = ((const float4*)out)[i];
    float r[4] = {v.x, v.y, v.z, v.w};
#pragma unroll
    for (int j = 0; j < 4; ++j) {
        int c = c0 + j;
        float mean = sums[c] * invn;
        float var = sums[64 + c] * invn - mean * mean;
        if (var < 0.0f) var = 0.0f;
        float scale = bnw[c] * rsqrtf(var + BN_EPS);
        float y = (r[j] - mean) * scale + bnb[c];
        r[j] = y > 0.0f ? y : 0.0f;
    }
    float4 o = {r[0], r[1], r[2], r[3]};
    ((float4*)out)[i] = o;
}

extern "C" void kernel_launch(void* const* d_in, const int* in_sizes, int n_in,
                              void* d_out, int out_size, void* d_ws, size_t ws_size,
                              hipStream_t stream) {
    const float* x = (const float*)d_in[0];
    const int* ei = (const int*)d_in[1];
    const float* W = (const float*)d_in[3];
    const float* bnw = (const float*)d_in[5];
    const float* bnb = (const float*)d_in[6];
    float* out = (float*)d_out;

    const int n = in_sizes[0] / D;   // 100000
    const int E = in_sizes[1] / 2;   // 1600000
    const int* src = ei;
    const int* dst = ei + E;

    // workspace: dinv (n floats) + sums (128 floats) ~400 KB
    float* dinv = (float*)d_ws;
    float* sums = dinv + n;

    k_deg_init<<<(n + 255) / 256, 256, 0, stream>>>(dinv, n);
    k_deg_edges<<<((E + 7) / 8 + 255) / 256, 256, 0, stream>>>(src, dst, dinv, E);
    k_dinv_f<<<(n + 255) / 256, 256, 0, stream>>>(dinv, n);

    k_agg_init<<<(n * (D / 4) + 255) / 256, 256, 0, stream>>>(x, dinv, out, n);

    // 8 edges per wave, 4 waves per block
    const int nwaves = (E + 7) / 8;
    k_scatter8<<<(nwaves + 3) / 4, 256, 0, stream>>>(src, dst, x, dinv, out, E);

    k_zero_stats<<<1, 128, 0, stream>>>(sums);
    k_gemm_stats<<<1024, 256, 0, stream>>>(out, W, sums, n);
    k_bn_apply<<<(n * (D / 4) + 255) / 256, 256, 0, stream>>>(out, sums, bnw, bnb, n);
}

// Round 7
// 449.054 us; speedup vs baseline: 1.2099x; 1.2099x over previous
//
#include <hip/hip_runtime.h>

#define NN 100000
#define D 64
#define BN_EPS 1e-5f

// ================= CSR build =================

__global__ void k_zero(int* cnt, float* sums, int n) {
    int i = blockIdx.x * blockDim.x + threadIdx.x;
    if (i < n) cnt[i] = 0;
    if (i < 128) sums[i] = 0.0f;
}

__global__ void k_count4(const int* __restrict__ src, const int* __restrict__ dst,
                         int* cnt, int E) {
    int t = blockIdx.x * blockDim.x + threadIdx.x;
    int e0 = t * 4;
    if (e0 >= E) return;
    if (e0 + 4 <= E) {
        int4 s4 = *(const int4*)(src + e0);
        int4 d4 = *(const int4*)(dst + e0);
        if (s4.x != d4.x) atomicAdd(&cnt[d4.x], 1);
        if (s4.y != d4.y) atomicAdd(&cnt[d4.y], 1);
        if (s4.z != d4.z) atomicAdd(&cnt[d4.z], 1);
        if (s4.w != d4.w) atomicAdd(&cnt[d4.w], 1);
    } else {
        for (int e = e0; e < E; ++e) {
            int s = src[e], d = dst[e];
            if (s != d) atomicAdd(&cnt[d], 1);
        }
    }
}

__global__ void k_dinv_i(const int* __restrict__ cnt, float* dinv, int n) {
    int i = blockIdx.x * blockDim.x + threadIdx.x;
    if (i < n) dinv[i] = rsqrtf((float)cnt[i] + 1.0f);  // +1 self loop
}

// exclusive scan of cnt -> row_ptr (3 phases)
__global__ __launch_bounds__(1024) void k_scanA(const int* __restrict__ cnt,
                                                int* __restrict__ row_ptr,
                                                int* __restrict__ bsum, int n) {
    __shared__ int sm[1024];
    int tid = threadIdx.x;
    int i = blockIdx.x * 1024 + tid;
    int v = (i < n) ? cnt[i] : 0;
    int xv = v;
    sm[tid] = xv;
    __syncthreads();
    for (int off = 1; off < 1024; off <<= 1) {
        int t = (tid >= off) ? sm[tid - off] : 0;
        __syncthreads();
        xv += t;
        sm[tid] = xv;
        __syncthreads();
    }
    if (i < n) row_ptr[i] = xv - v;
    if (tid == 1023) bsum[blockIdx.x] = xv;
}

__global__ void k_scanB(int* bsum, int nb) {
    __shared__ int sm[128];
    int tid = threadIdx.x;
    int v = (tid < nb) ? bsum[tid] : 0;
    int xv = v;
    sm[tid] = xv;
    __syncthreads();
    for (int off = 1; off < 128; off <<= 1) {
        int t = (tid >= off) ? sm[tid - off] : 0;
        __syncthreads();
        xv += t;
        sm[tid] = xv;
        __syncthreads();
    }
    if (tid < nb) bsum[tid] = xv - v;
}

__global__ void k_scanC(int* __restrict__ row_ptr, int* __restrict__ cursor,
                        const int* __restrict__ bsum, int n) {
    int i = blockIdx.x * blockDim.x + threadIdx.x;
    if (i < n) {
        int r = row_ptr[i] + bsum[i >> 10];
        row_ptr[i] = r;
        cursor[i] = r;
    }
}

__global__ void k_place4(const int* __restrict__ src, const int* __restrict__ dst,
                         int* cursor, int* __restrict__ srcid, int E) {
    int t = blockIdx.x * blockDim.x + threadIdx.x;
    int e0 = t * 4;
    if (e0 >= E) return;
    if (e0 + 4 <= E) {
        int4 s4 = *(const int4*)(src + e0);
        int4 d4 = *(const int4*)(dst + e0);
        // 4 independent chains: cursor-atomic -> scattered write
        if (s4.x != d4.x) srcid[atomicAdd(&cursor[d4.x], 1)] = s4.x;
        if (s4.y != d4.y) srcid[atomicAdd(&cursor[d4.y], 1)] = s4.y;
        if (s4.z != d4.z) srcid[atomicAdd(&cursor[d4.z], 1)] = s4.z;
        if (s4.w != d4.w) srcid[atomicAdd(&cursor[d4.w], 1)] = s4.w;
    } else {
        for (int e = e0; e < E; ++e) {
            int s = src[e], d = dst[e];
            if (s != d) srcid[atomicAdd(&cursor[d], 1)] = s;
        }
    }
}

// ================= fused gather + GEMM + BN stats =================
// one wave per node (grid-stride), lane = channel; agg row never leaves registers.
__global__ __launch_bounds__(256) void k_gather_gemm_stats(
        const int* __restrict__ row_ptr, const int* __restrict__ cnt,
        const int* __restrict__ srcid, const float* __restrict__ x,
        const float* __restrict__ dinv, const float* __restrict__ W,
        float* __restrict__ out, float* sums, int n) {
    __shared__ float Ws[64 * 64];
    int tid = threadIdx.x;
    for (int i = tid; i < 64 * 64; i += 256) Ws[i] = W[i];
    __syncthreads();
    int wave = tid >> 6, lane = tid & 63;
    float s = 0.0f, sq = 0.0f;
    for (int d = blockIdx.x * 4 + wave; d < n; d += gridDim.x * 4) {
        int base = row_ptr[d];
        int c = cnt[d];
        float did = dinv[d];
        float acc = x[(size_t)d * D + lane] * did * did;  // self loop
        int j = 0;
        for (; j + 8 <= c; j += 8) {
            int si[8];
            float wv[8], xv[8];
#pragma unroll
            for (int u = 0; u < 8; ++u) si[u] = srcid[base + j + u];
#pragma unroll
            for (int u = 0; u < 8; ++u) wv[u] = dinv[si[u]] * did;
#pragma unroll
            for (int u = 0; u < 8; ++u) xv[u] = x[(size_t)si[u] * D + lane];
#pragma unroll
            for (int u = 0; u < 8; ++u) acc += xv[u] * wv[u];
        }
        for (; j < c; ++j) {
            int si = srcid[base + j];
            acc += x[(size_t)si * D + lane] * (dinv[si] * did);
        }
        // GEMM: out_row = acc_row @ W
        float o = 0.0f;
#pragma unroll
        for (int k = 0; k < 64; ++k) {
            o += __shfl(acc, k) * Ws[k * 64 + lane];
        }
        out[(size_t)d * D + lane] = o;
        s += o;
        sq += o * o;
    }
    __shared__ float ls[4][64], lq[4][64];
    ls[wave][lane] = s;
    lq[wave][lane] = sq;
    __syncthreads();
    if (wave == 0) {
        float ts = ls[0][lane] + ls[1][lane] + ls[2][lane] + ls[3][lane];
        float tq = lq[0][lane] + lq[1][lane] + lq[2][lane] + lq[3][lane];
        atomicAdd(&sums[lane], ts);
        atomicAdd(&sums[64 + lane], tq);
    }
}

// ================= BN apply + ReLU (float4, in place) =================
// GCN bias b cancels exactly in BatchNorm: omitted.
__global__ void k_bn_apply(float* out, const float* __restrict__ sums,
                           const float* __restrict__ bnw, const float* __restrict__ bnb,
                           int n) {
    int i = blockIdx.x * blockDim.x + threadIdx.x;
    int total = n * (D / 4);
    if (i >= total) return;
    int c0 = (i * 4) & 63;
    const float invn = 1.0f / (float)NN;
    float4 v = ((const float4*)out)[i];
    float r[4] = {v.x, v.y, v.z, v.w};
#pragma unroll
    for (int j = 0; j < 4; ++j) {
        int c = c0 + j;
        float mean = sums[c] * invn;
        float var = sums[64 + c] * invn - mean * mean;
        if (var < 0.0f) var = 0.0f;
        float scale = bnw[c] * rsqrtf(var + BN_EPS);
        float y = (r[j] - mean) * scale + bnb[c];
        r[j] = y > 0.0f ? y : 0.0f;
    }
    float4 o = {r[0], r[1], r[2], r[3]};
    ((float4*)out)[i] = o;
}

// ================= fallback (small ws): atomic scatter (R5 path) =================

__global__ void k_deg_init(float* deg, int n) {
    int i = blockIdx.x * blockDim.x + threadIdx.x;
    if (i < n) deg[i] = 1.0f;
}

__global__ void k_deg_edges(const int* __restrict__ src, const int* __restrict__ dst,
                            float* deg, int E) {
    int e = blockIdx.x * blockDim.x + threadIdx.x;
    if (e < E) {
        int s = src[e], d = dst[e];
        if (s != d) atomicAdd(&deg[d], 1.0f);
    }
}

__global__ void k_dinv_f(float* deg, int n) {
    int i = blockIdx.x * blockDim.x + threadIdx.x;
    if (i < n) deg[i] = rsqrtf(deg[i]);
}

__global__ void k_agg_init(const float* __restrict__ x, const float* __restrict__ dinv,
                           float* __restrict__ out, int n) {
    int i = blockIdx.x * blockDim.x + threadIdx.x;
    int total = n * (D / 4);
    if (i >= total) return;
    int row = i >> 4;
    float di = dinv[row];
    float sc = di * di;
    float4 v = ((const float4*)x)[i];
    v.x *= sc; v.y *= sc; v.z *= sc; v.w *= sc;
    ((float4*)out)[i] = v;
}

__global__ __launch_bounds__(256) void k_scatter(const int* __restrict__ src,
                                                 const int* __restrict__ dst,
                                                 const float* __restrict__ x,
                                                 const float* __restrict__ dinv,
                                                 float* out, int E) {
    int gw = (int)((blockIdx.x * blockDim.x + threadIdx.x) >> 6);
    int lane = threadIdx.x & 63;
    if (gw >= E) return;
    int s = src[gw], d = dst[gw];
    if (s == d) return;
    float w = dinv[s] * dinv[d];
    atomicAdd(&out[(size_t)d * D + lane], x[(size_t)s * D + lane] * w);
}

__global__ void k_zero_stats(float* sums) {
    int i = threadIdx.x;
    if (i < 128) sums[i] = 0.0f;
}

__global__ __launch_bounds__(256) void k_gemm_stats(float* __restrict__ out,
                                                    const float* __restrict__ W,
                                                    float* sums, int n) {
    __shared__ float Ws[64 * 64];
    int tid = threadIdx.x;
    for (int i = tid; i < 64 * 64; i += 256) Ws[i] = W[i];
    __syncthreads();
    int wave = tid >> 6, lane = tid & 63;
    float s = 0.0f, sq = 0.0f;
    for (int row = blockIdx.x * 4 + wave; row < n; row += gridDim.x * 4) {
        float xv = out[(size_t)row * D + lane];
        float acc = 0.0f;
#pragma unroll
        for (int k = 0; k < 64; ++k) {
            acc += __shfl(xv, k) * Ws[k * 64 + lane];
        }
        out[(size_t)row * D + lane] = acc;
        s += acc;
        sq += acc * acc;
    }
    __shared__ float ls[4][64], lq[4][64];
    ls[wave][lane] = s;
    lq[wave][lane] = sq;
    __syncthreads();
    if (wave == 0) {
        float ts = ls[0][lane] + ls[1][lane] + ls[2][lane] + ls[3][lane];
        float tq = lq[0][lane] + lq[1][lane] + lq[2][lane] + lq[3][lane];
        atomicAdd(&sums[lane], ts);
        atomicAdd(&sums[64 + lane], tq);
    }
}

extern "C" void kernel_launch(void* const* d_in, const int* in_sizes, int n_in,
                              void* d_out, int out_size, void* d_ws, size_t ws_size,
                              hipStream_t stream) {
    const float* x = (const float*)d_in[0];
    const int* ei = (const int*)d_in[1];
    const float* W = (const float*)d_in[3];
    const float* bnw = (const float*)d_in[5];
    const float* bnb = (const float*)d_in[6];
    float* out = (float*)d_out;

    const int n = in_sizes[0] / D;   // 100000
    const int E = in_sizes[1] / 2;   // 1600000
    const int* src = ei;
    const int* dst = ei + E;

    const size_t need = ((size_t)4 * n + (size_t)E + 512) * 4;  // ~8.0 MB

    if (ws_size >= need) {
        int* cnt = (int*)d_ws;
        int* row_ptr = cnt + n;
        int* cursor = row_ptr + n;
        float* dinv = (float*)(cursor + n);
        int* srcid = (int*)(dinv + n);
        int* bsum = srcid + E;             // 128 ints
        float* sums = (float*)(bsum + 128);  // 128 floats

        const int nb = (n + 1023) / 1024;  // 98

        k_zero<<<(n + 255) / 256, 256, 0, stream>>>(cnt, sums, n);
        k_count4<<<((E + 3) / 4 + 255) / 256, 256, 0, stream>>>(src, dst, cnt, E);
        k_dinv_i<<<(n + 255) / 256, 256, 0, stream>>>(cnt, dinv, n);
        k_scanA<<<nb, 1024, 0, stream>>>(cnt, row_ptr, bsum, n);
        k_scanB<<<1, 128, 0, stream>>>(bsum, nb);
        k_scanC<<<(n + 255) / 256, 256, 0, stream>>>(row_ptr, cursor, bsum, n);
        k_place4<<<((E + 3) / 4 + 255) / 256, 256, 0, stream>>>(src, dst, cursor, srcid, E);

        k_gather_gemm_stats<<<1024, 256, 0, stream>>>(row_ptr, cnt, srcid, x, dinv, W,
                                                      out, sums, n);
        k_bn_apply<<<(n * (D / 4) + 255) / 256, 256, 0, stream>>>(out, sums, bnw, bnb, n);
    } else {
        // fallback: atomic scatter path
        float* dinv = (float*)d_ws;
        float* sums = dinv + n;
        k_deg_init<<<(n + 255) / 256, 256, 0, stream>>>(dinv, n);
        k_deg_edges<<<(E + 255) / 256, 256, 0, stream>>>(src, dst, dinv, E);
        k_dinv_f<<<(n + 255) / 256, 256, 0, stream>>>(dinv, n);
        k_agg_init<<<(n * (D / 4) + 255) / 256, 256, 0, stream>>>(x, dinv, out, n);
        k_scatter<<<(E + 3) / 4, 256, 0, stream>>>(src, dst, x, dinv, out, E);
        k_zero_stats<<<1, 128, 0, stream>>>(sums);
        k_gemm_stats<<<1024, 256, 0, stream>>>(out, W, sums, n);
        k_bn_apply<<<(n * (D / 4) + 255) / 256, 256, 0, stream>>>(out, sums, bnw, bnb, n);
    }
}

// Round 8
// 397.449 us; speedup vs baseline: 1.3670x; 1.1298x over previous
//
#include <hip/hip_runtime.h>

#define NN 100000
#define D 64
#define BN_EPS 1e-5f

// ================= CSR build =================

__global__ void k_zero(int* cnt, float* sums8, int n) {
    int i = blockIdx.x * blockDim.x + threadIdx.x;
    if (i < n) cnt[i] = 0;
    if (i < 1152) sums8[i] = 0.0f;  // 8*128 slots + 128 final
}

__global__ void k_count4(const int* __restrict__ src, const int* __restrict__ dst,
                         int* cnt, int E) {
    int t = blockIdx.x * blockDim.x + threadIdx.x;
    int e0 = t * 4;
    if (e0 >= E) return;
    if (e0 + 4 <= E) {
        int4 s4 = *(const int4*)(src + e0);
        int4 d4 = *(const int4*)(dst + e0);
        if (s4.x != d4.x) atomicAdd(&cnt[d4.x], 1);
        if (s4.y != d4.y) atomicAdd(&cnt[d4.y], 1);
        if (s4.z != d4.z) atomicAdd(&cnt[d4.z], 1);
        if (s4.w != d4.w) atomicAdd(&cnt[d4.w], 1);
    } else {
        for (int e = e0; e < E; ++e) {
            int s = src[e], d = dst[e];
            if (s != d) atomicAdd(&cnt[d], 1);
        }
    }
}

__global__ void k_dinv_i(const int* __restrict__ cnt, float* dinv, int n) {
    int i = blockIdx.x * blockDim.x + threadIdx.x;
    if (i < n) dinv[i] = rsqrtf((float)cnt[i] + 1.0f);  // +1 self loop
}

// exclusive scan of cnt -> row_ptr (3 phases)
__global__ __launch_bounds__(1024) void k_scanA(const int* __restrict__ cnt,
                                                int* __restrict__ row_ptr,
                                                int* __restrict__ bsum, int n) {
    __shared__ int sm[1024];
    int tid = threadIdx.x;
    int i = blockIdx.x * 1024 + tid;
    int v = (i < n) ? cnt[i] : 0;
    int xv = v;
    sm[tid] = xv;
    __syncthreads();
    for (int off = 1; off < 1024; off <<= 1) {
        int t = (tid >= off) ? sm[tid - off] : 0;
        __syncthreads();
        xv += t;
        sm[tid] = xv;
        __syncthreads();
    }
    if (i < n) row_ptr[i] = xv - v;
    if (tid == 1023) bsum[blockIdx.x] = xv;
}

__global__ void k_scanB(int* bsum, int nb) {
    __shared__ int sm[128];
    int tid = threadIdx.x;
    int v = (tid < nb) ? bsum[tid] : 0;
    int xv = v;
    sm[tid] = xv;
    __syncthreads();
    for (int off = 1; off < 128; off <<= 1) {
        int t = (tid >= off) ? sm[tid - off] : 0;
        __syncthreads();
        xv += t;
        sm[tid] = xv;
        __syncthreads();
    }
    if (tid < nb) bsum[tid] = xv - v;
}

__global__ void k_scanC(int* __restrict__ row_ptr, int* __restrict__ cursor,
                        const int* __restrict__ bsum, int n) {
    int i = blockIdx.x * blockDim.x + threadIdx.x;
    if (i < n) {
        int r = row_ptr[i] + bsum[i >> 10];
        row_ptr[i] = r;
        cursor[i] = r;
    }
}

__global__ void k_place8(const int* __restrict__ src, const int* __restrict__ dst,
                         int* cursor, int* __restrict__ srcid, int E) {
    int t = blockIdx.x * blockDim.x + threadIdx.x;
    int e0 = t * 8;
    if (e0 >= E) return;
    if (e0 + 8 <= E) {
        int4 sa = *(const int4*)(src + e0);
        int4 sb = *(const int4*)(src + e0 + 4);
        int4 da = *(const int4*)(dst + e0);
        int4 db = *(const int4*)(dst + e0 + 4);
        // 8 independent chains: cursor-atomic -> scattered write
        if (sa.x != da.x) srcid[atomicAdd(&cursor[da.x], 1)] = sa.x;
        if (sa.y != da.y) srcid[atomicAdd(&cursor[da.y], 1)] = sa.y;
        if (sa.z != da.z) srcid[atomicAdd(&cursor[da.z], 1)] = sa.z;
        if (sa.w != da.w) srcid[atomicAdd(&cursor[da.w], 1)] = sa.w;
        if (sb.x != db.x) srcid[atomicAdd(&cursor[db.x], 1)] = sb.x;
        if (sb.y != db.y) srcid[atomicAdd(&cursor[db.y], 1)] = sb.y;
        if (sb.z != db.z) srcid[atomicAdd(&cursor[db.z], 1)] = sb.z;
        if (sb.w != db.w) srcid[atomicAdd(&cursor[db.w], 1)] = sb.w;
    } else {
        for (int e = e0; e < E; ++e) {
            int s = src[e], d = dst[e];
            if (s != d) srcid[atomicAdd(&cursor[d], 1)] = s;
        }
    }
}

// ================= fused gather + GEMM + BN stats =================
// one wave per node (grid-stride), lane = channel; agg row never leaves registers.
// stats flush goes to 8 padded slots (blockIdx&7) -> <=512 atomics/address, hidden.
__global__ __launch_bounds__(256) void k_gather_gemm_stats(
        const int* __restrict__ row_ptr, const int* __restrict__ cnt,
        const int* __restrict__ srcid, const float* __restrict__ x,
        const float* __restrict__ dinv, const float* __restrict__ W,
        float* __restrict__ out, float* sums8, int n) {
    __shared__ float Ws[64 * 64];
    int tid = threadIdx.x;
    for (int i = tid; i < 64 * 64; i += 256) Ws[i] = W[i];
    __syncthreads();
    int wave = tid >> 6, lane = tid & 63;
    float s = 0.0f, sq = 0.0f;
    for (int d = blockIdx.x * 4 + wave; d < n; d += gridDim.x * 4) {
        int base = row_ptr[d];
        int c = cnt[d];
        float did = dinv[d];
        float acc = x[(size_t)d * D + lane] * did * did;  // self loop
        int j = 0;
        for (; j + 8 <= c; j += 8) {
            int si[8];
            float wv[8], xv[8];
#pragma unroll
            for (int u = 0; u < 8; ++u) si[u] = srcid[base + j + u];
#pragma unroll
            for (int u = 0; u < 8; ++u) wv[u] = dinv[si[u]] * did;
#pragma unroll
            for (int u = 0; u < 8; ++u) xv[u] = x[(size_t)si[u] * D + lane];
#pragma unroll
            for (int u = 0; u < 8; ++u) acc += xv[u] * wv[u];
        }
        for (; j < c; ++j) {
            int si = srcid[base + j];
            acc += x[(size_t)si * D + lane] * (dinv[si] * did);
        }
        // GEMM: out_row = acc_row @ W
        float o = 0.0f;
#pragma unroll
        for (int k = 0; k < 64; ++k) {
            o += __shfl(acc, k) * Ws[k * 64 + lane];
        }
        out[(size_t)d * D + lane] = o;
        s += o;
        sq += o * o;
    }
    __shared__ float ls[4][64], lq[4][64];
    ls[wave][lane] = s;
    lq[wave][lane] = sq;
    __syncthreads();
    if (wave == 0) {
        float ts = ls[0][lane] + ls[1][lane] + ls[2][lane] + ls[3][lane];
        float tq = lq[0][lane] + lq[1][lane] + lq[2][lane] + lq[3][lane];
        float* slot = sums8 + (size_t)(blockIdx.x & 7) * 128;
        atomicAdd(&slot[lane], ts);
        atomicAdd(&slot[64 + lane], tq);
    }
}

// fold 8 slots -> final sums (stored at sums8 + 1024)
__global__ void k_finalize(float* sums8) {
    int i = threadIdx.x;  // 128 threads
    float s = 0.0f;
#pragma unroll
    for (int j = 0; j < 8; ++j) s += sums8[j * 128 + i];
    sums8[1024 + i] = s;
}

// ================= BN apply + ReLU (float4, in place) =================
// GCN bias b cancels exactly in BatchNorm: omitted.
__global__ void k_bn_apply(float* out, const float* __restrict__ sums,
                           const float* __restrict__ bnw, const float* __restrict__ bnb,
                           int n) {
    int i = blockIdx.x * blockDim.x + threadIdx.x;
    int total = n * (D / 4);
    if (i >= total) return;
    int c0 = (i * 4) & 63;
    const float invn = 1.0f / (float)NN;
    float4 v = ((const float4*)out)[i];
    float r[4] = {v.x, v.y, v.z, v.w};
#pragma unroll
    for (int j = 0; j < 4; ++j) {
        int c = c0 + j;
        float mean = sums[c] * invn;
        float var = sums[64 + c] * invn - mean * mean;
        if (var < 0.0f) var = 0.0f;
        float scale = bnw[c] * rsqrtf(var + BN_EPS);
        float y = (r[j] - mean) * scale + bnb[c];
        r[j] = y > 0.0f ? y : 0.0f;
    }
    float4 o = {r[0], r[1], r[2], r[3]};
    ((float4*)out)[i] = o;
}

// ================= fallback (small ws): atomic scatter =================

__global__ void k_deg_init(float* deg, int n) {
    int i = blockIdx.x * blockDim.x + threadIdx.x;
    if (i < n) deg[i] = 1.0f;
}

__global__ void k_deg_edges(const int* __restrict__ src, const int* __restrict__ dst,
                            float* deg, int E) {
    int e = blockIdx.x * blockDim.x + threadIdx.x;
    if (e < E) {
        int s = src[e], d = dst[e];
        if (s != d) atomicAdd(&deg[d], 1.0f);
    }
}

__global__ void k_dinv_f(float* deg, int n) {
    int i = blockIdx.x * blockDim.x + threadIdx.x;
    if (i < n) deg[i] = rsqrtf(deg[i]);
}

__global__ void k_agg_init(const float* __restrict__ x, const float* __restrict__ dinv,
                           float* __restrict__ out, int n) {
    int i = blockIdx.x * blockDim.x + threadIdx.x;
    int total = n * (D / 4);
    if (i >= total) return;
    int row = i >> 4;
    float di = dinv[row];
    float sc = di * di;
    float4 v = ((const float4*)x)[i];
    v.x *= sc; v.y *= sc; v.z *= sc; v.w *= sc;
    ((float4*)out)[i] = v;
}

__global__ __launch_bounds__(256) void k_scatter(const int* __restrict__ src,
                                                 const int* __restrict__ dst,
                                                 const float* __restrict__ x,
                                                 const float* __restrict__ dinv,
                                                 float* out, int E) {
    int gw = (int)((blockIdx.x * blockDim.x + threadIdx.x) >> 6);
    int lane = threadIdx.x & 63;
    if (gw >= E) return;
    int s = src[gw], d = dst[gw];
    if (s == d) return;
    float w = dinv[s] * dinv[d];
    atomicAdd(&out[(size_t)d * D + lane], x[(size_t)s * D + lane] * w);
}

__global__ void k_zero_stats(float* sums) {
    int i = threadIdx.x;
    if (i < 128) sums[i] = 0.0f;
}

__global__ __launch_bounds__(256) void k_gemm_stats(float* __restrict__ out,
                                                    const float* __restrict__ W,
                                                    float* sums, int n) {
    __shared__ float Ws[64 * 64];
    int tid = threadIdx.x;
    for (int i = tid; i < 64 * 64; i += 256) Ws[i] = W[i];
    __syncthreads();
    int wave = tid >> 6, lane = tid & 63;
    float s = 0.0f, sq = 0.0f;
    for (int row = blockIdx.x * 4 + wave; row < n; row += gridDim.x * 4) {
        float xv = out[(size_t)row * D + lane];
        float acc = 0.0f;
#pragma unroll
        for (int k = 0; k < 64; ++k) {
            acc += __shfl(xv, k) * Ws[k * 64 + lane];
        }
        out[(size_t)row * D + lane] = acc;
        s += acc;
        sq += acc * acc;
    }
    __shared__ float ls[4][64], lq[4][64];
    ls[wave][lane] = s;
    lq[wave][lane] = sq;
    __syncthreads();
    if (wave == 0) {
        float ts = ls[0][lane] + ls[1][lane] + ls[2][lane] + ls[3][lane];
        float tq = lq[0][lane] + lq[1][lane] + lq[2][lane] + lq[3][lane];
        atomicAdd(&sums[lane], ts);
        atomicAdd(&sums[64 + lane], tq);
    }
}

extern "C" void kernel_launch(void* const* d_in, const int* in_sizes, int n_in,
                              void* d_out, int out_size, void* d_ws, size_t ws_size,
                              hipStream_t stream) {
    const float* x = (const float*)d_in[0];
    const int* ei = (const int*)d_in[1];
    const float* W = (const float*)d_in[3];
    const float* bnw = (const float*)d_in[5];
    const float* bnb = (const float*)d_in[6];
    float* out = (float*)d_out;

    const int n = in_sizes[0] / D;   // 100000
    const int E = in_sizes[1] / 2;   // 1600000
    const int* src = ei;
    const int* dst = ei + E;

    const size_t need = ((size_t)4 * n + (size_t)E + 1408) * 4;  // ~8.0 MB

    if (ws_size >= need) {
        int* cnt = (int*)d_ws;
        int* row_ptr = cnt + n;
        int* cursor = row_ptr + n;
        float* dinv = (float*)(cursor + n);
        int* srcid = (int*)(dinv + n);
        int* bsum = srcid + E;                 // 128 ints
        float* sums8 = (float*)(bsum + 128);   // 8*128 slots + 128 final
        float* sums = sums8 + 1024;

        const int nb = (n + 1023) / 1024;  // 98

        k_zero<<<(n + 255) / 256, 256, 0, stream>>>(cnt, sums8, n);
        k_count4<<<((E + 3) / 4 + 255) / 256, 256, 0, stream>>>(src, dst, cnt, E);
        k_dinv_i<<<(n + 255) / 256, 256, 0, stream>>>(cnt, dinv, n);
        k_scanA<<<nb, 1024, 0, stream>>>(cnt, row_ptr, bsum, n);
        k_scanB<<<1, 128, 0, stream>>>(bsum, nb);
        k_scanC<<<(n + 255) / 256, 256, 0, stream>>>(row_ptr, cursor, bsum, n);
        k_place8<<<((E + 7) / 8 + 255) / 256, 256, 0, stream>>>(src, dst, cursor, srcid, E);

        k_gather_gemm_stats<<<4096, 256, 0, stream>>>(row_ptr, cnt, srcid, x, dinv, W,
                                                      out, sums8, n);
        k_finalize<<<1, 128, 0, stream>>>(sums8);
        k_bn_apply<<<(n * (D / 4) + 255) / 256, 256, 0, stream>>>(out, sums, bnw, bnb, n);
    } else {
        // fallback: atomic scatter path
        float* dinv = (float*)d_ws;
        float* sums = dinv + n;
        k_deg_init<<<(n + 255) / 256, 256, 0, stream>>>(dinv, n);
        k_deg_edges<<<(E + 255) / 256, 256, 0, stream>>>(src, dst, dinv, E);
        k_dinv_f<<<(n + 255) / 256, 256, 0, stream>>>(dinv, n);
        k_agg_init<<<(n * (D / 4) + 255) / 256, 256, 0, stream>>>(x, dinv, out, n);
        k_scatter<<<(E + 3) / 4, 256, 0, stream>>>(src, dst, x, dinv, out, E);
        k_zero_stats<<<1, 128, 0, stream>>>(sums);
        k_gemm_stats<<<1024, 256, 0, stream>>>(out, W, sums, n);
        k_bn_apply<<<(n * (D / 4) + 255) / 256, 256, 0, stream>>>(out, sums, bnw, bnb, n);
    }
}